// Round 6
// baseline (196.333 us; speedup 1.0000x reference)
//
#include <hip/hip_runtime.h>
#include <math.h>

#define KTR 96
#define DIM 256
#define PB  40
#define CH  8
#define MDIM 3840
#define KK  512             // A(test): [hi | lo*4096]; B(enroll): [lo*4096 | hi]
#define BM 160              // test rows (l,j): 4 complete groups
#define BNS 128             // enroll cols staged
#define BNV 120             // enroll cols valid: 3 complete groups
#define LDR 72              // f16 per LDS row: 64 data + 8 pad (144 B stride)
#define NTAB 2113           // gate table nodes, h = 2^-10, x = (i-1056)/1024

typedef _Float16 v8h __attribute__((ext_vector_type(8)));
typedef float    v4f __attribute__((ext_vector_type(4)));

__device__ __forceinline__ float gate_ref(float x, const float* w, const float* b, const float* v) {
    float g = 0.f;
    #pragma unroll
    for (int c = 0; c < CH; ++c) g = fmaf(v[c], tanhf(fmaf(w[c], x, b[c])), g);
    return g;
}

// ---------------- Kernel 1: L2-normalize + f16 hi/lo split (compact rows) + gate table ----------------
__global__ __launch_bounds__(256) void k_norm(const float* __restrict__ enroll,
                                              const float* __restrict__ test,
                                              const float* __restrict__ fc1_w,
                                              const float* __restrict__ fc1_b,
                                              const float* __restrict__ fc2_w,
                                              _Float16* __restrict__ XT,
                                              _Float16* __restrict__ XE,
                                              float2* __restrict__ gtabG) {
    int b = blockIdx.x, tid = threadIdx.x;

    if (b >= 2 * KTR) {                        // 9 table-builder blocks
        int i = (b - 2 * KTR) * 256 + tid;
        if (i < NTAB) {
            float w[CH], bb[CH], vv[CH];
            #pragma unroll
            for (int c = 0; c < CH; ++c) { w[c] = fc1_w[c]; bb[c] = fc1_b[c]; vv[c] = fc2_w[c]; }
            float x0 = (float)(i - 1056) * 0.0009765625f;
            float g0 = gate_ref(x0, w, bb, vv);
            float g1 = gate_ref(x0 + 0.0009765625f, w, bb, vv);
            gtabG[i] = make_float2(g0, g1 - g0);
        }
        return;
    }

    bool isE = (b < KTR);
    int k = isE ? b : b - KTR;
    const float* src = (isE ? enroll : test) + (size_t)k * DIM * PB;

    __shared__ float S[DIM * 41];
    __shared__ float part[6 * PB];
    __shared__ float rn[PB];

    for (int i = tid; i < DIM * PB / 4; i += 256) {
        float4 v = ((const float4*)src)[i];
        int d = i / 10, c = i - d * 10;
        float* p = &S[d * 41 + c * 4];
        p[0] = v.x; p[1] = v.y; p[2] = v.z; p[3] = v.w;
    }
    __syncthreads();
    if (tid < 240) {
        int g = tid / PB, p = tid - (tid / PB) * PB;
        float acc = 0.f;
        for (int d = g; d < DIM; d += 6) {
            float x = S[d * 41 + p];
            acc = fmaf(x, x, acc);
        }
        part[g * PB + p] = acc;
    }
    __syncthreads();
    if (tid < PB) {
        float s = 0.f;
        #pragma unroll
        for (int g = 0; g < 6; ++g) s += part[g * PB + tid];
        rn[tid] = 1.0f / fmaxf(sqrtf(s), 1e-12f);
    }
    __syncthreads();

    // 1280 jobs: (p, 8-wide d-group) -> two uint4 stores (hi, lo')
    _Float16* dst = isE ? XE : XT;
    #pragma unroll
    for (int i = 0; i < 5; ++i) {
        int idx = tid + i * 256;
        int p = idx >> 5, dg = idx & 31;
        int d0 = dg * 8;
        float r = rn[p];
        union { _Float16 f[8]; uint4 u; } hv, lv;
        #pragma unroll
        for (int j = 0; j < 8; ++j) {
            float x = S[(d0 + j) * 41 + p] * r;
            _Float16 h = (_Float16)x;
            hv.f[j] = h;
            lv.f[j] = (_Float16)((x - (float)h) * 4096.0f);
        }
        size_t base = (size_t)(k * PB + p) * KK;
        if (isE) {  // enroll: [lo' | hi]
            *(uint4*)(dst + base + d0)       = lv.u;
            *(uint4*)(dst + base + 256 + d0) = hv.u;
        } else {    // test:   [hi | lo']
            *(uint4*)(dst + base + d0)       = hv.u;
            *(uint4*)(dst + base + 256 + d0) = lv.u;
        }
    }
}

// ---------------- Kernel 2: BK=64 reg-staged MFMA GEMM + gate1 + j-sum + gate2 + i-sum ----------------
// __launch_bounds__(256, 2): round-5's (256,3) capped unified VGPR+AGPR at ~170/wave;
// live set (acc 80 + frags 36 + staging 36 + ptrs ~30) overflowed -> per-iter scratch
// spill = 343 MB HBM writes. min-waves=2 gives 256-reg budget; compiler may still land
// low enough for 3 blocks/CU (bound is a minimum, not a target).
__global__ __launch_bounds__(256, 2) void k_gemm(const _Float16* __restrict__ XT,
                                                 const _Float16* __restrict__ XE,
                                                 const float2* __restrict__ gtab,
                                                 const float* __restrict__ fc1_w,
                                                 const float* __restrict__ fc1_b,
                                                 const float* __restrict__ fc2_w,
                                                 float* __restrict__ out) {
    __shared__ __align__(16) _Float16 LA[BM * LDR];    // 23040 B
    __shared__ __align__(16) _Float16 LB[BNS * LDR];   // 18432 B
    __shared__ float ph2[4][132];                      // block-local pho2 [lgroup][col]

    int tid = threadIdx.x, lane = tid & 63, wv = tid >> 6;
    int m0 = blockIdx.y * BM;
    int n0 = blockIdx.x * BNV;                         // steps of 120; stages 128 (8 masked)

    // staging jobs: A 1280 uint4 (5/thread), B 1024 uint4 (4/thread)
    const uint4* gA[5]; int lAo[5];
    #pragma unroll
    for (int j = 0; j < 5; ++j) {
        int idx = tid + j * 256;
        int r = idx >> 3, c = idx & 7;
        gA[j]  = (const uint4*)(XT + (size_t)(m0 + r) * KK) + c;
        lAo[j] = r * LDR + c * 8;
    }
    const uint4* gB[4]; int lBo[4];
    #pragma unroll
    for (int j = 0; j < 4; ++j) {
        int idx = tid + j * 256;
        int r = idx >> 3, c = idx & 7;
        int gr = n0 + r; if (gr > MDIM - 1) gr = MDIM - 1;   // tail overread clamp
        gB[j]  = (const uint4*)(XE + (size_t)gr * KK) + c;
        lBo[j] = r * LDR + c * 8;
    }

    int wm = (wv & 1) * 80;
    int wn = (wv >> 1) * 64;
    int r15 = lane & 15, q4 = lane >> 4;

    int aoff[5], boff[4];
    #pragma unroll
    for (int mt = 0; mt < 5; ++mt) aoff[mt] = (wm + mt * 16 + r15) * LDR + q4 * 8;
    #pragma unroll
    for (int nt = 0; nt < 4; ++nt) boff[nt] = (wn + nt * 16 + r15) * LDR + q4 * 8;

    v4f acc[5][4];
    #pragma unroll
    for (int mt = 0; mt < 5; ++mt)
        #pragma unroll
        for (int nt = 0; nt < 4; ++nt)
            acc[mt][nt] = (v4f)0.f;

    uint4 sa[5], sb[4];
    // iters 0..7: A [hi|lo'] vs B [lo'|hi]  (cross terms x4096)
    // iters 8..11: A hi vs B hi             (hi*hi), acc pre-scaled by 2^-12
    #define GLOAD(IT) {                                                      \
        int ka = ((IT) < 8) ? (IT) * 8 : ((IT) - 8) * 8;                     \
        int kb = ((IT) < 8) ? (IT) * 8 : 32 + ((IT) - 8) * 8;                \
        _Pragma("unroll")                                                    \
        for (int j = 0; j < 5; ++j) sa[j] = gA[j][ka];                       \
        _Pragma("unroll")                                                    \
        for (int j = 0; j < 4; ++j) sb[j] = gB[j][kb]; }

    GLOAD(0);
    for (int it = 0; it < 12; ++it) {
        __syncthreads();                       // prev iter's frag reads done
        #pragma unroll
        for (int j = 0; j < 5; ++j) *(uint4*)(LA + lAo[j]) = sa[j];
        #pragma unroll
        for (int j = 0; j < 4; ++j) *(uint4*)(LB + lBo[j]) = sb[j];
        __syncthreads();
        if (it < 11) GLOAD(it + 1);            // in flight across the whole MFMA phase

        if (it == 8) {                         // cross complete: scale by 2^-12 (exact)
            #pragma unroll
            for (int mt = 0; mt < 5; ++mt)
                #pragma unroll
                for (int nt = 0; nt < 4; ++nt)
                    acc[mt][nt] *= 0.000244140625f;
        }

        #pragma unroll
        for (int h = 0; h < 2; ++h) {
            v8h af[5], bf[4];
            #pragma unroll
            for (int mt = 0; mt < 5; ++mt) af[mt] = *(const v8h*)(LA + aoff[mt] + h * 32);
            #pragma unroll
            for (int nt = 0; nt < 4; ++nt) bf[nt] = *(const v8h*)(LB + boff[nt] + h * 32);
            #pragma unroll
            for (int mt = 0; mt < 5; ++mt)
                #pragma unroll
                for (int nt = 0; nt < 4; ++nt)
                    acc[mt][nt] = __builtin_amdgcn_mfma_f32_16x16x32_f16(af[mt], bf[nt], acc[mt][nt], 0, 0, 0);
        }
    }
    #undef GLOAD

    // ---- phase 1: gate1 (global table) + j-sum within wave -> ph2[lgroup][col] ----
    const float inv40 = 1.0f / (40.0f + 1e-6f);
    int lgb = wm / 40;                         // 0 or 2 (block-local l-group base)
    #pragma unroll
    for (int nt = 0; nt < 4; ++nt) {
        float s0 = 0.f, s1 = 0.f, t2 = 0.f;
        #pragma unroll
        for (int mt = 0; mt < 5; ++mt) {
            #pragma unroll
            for (int r = 0; r < 4; ++r) {
                float x = acc[mt][nt][r];
                float u = fmaf(x, 1024.0f, 1056.0f);
                int i = (int)u;
                i = min(max(i, 0), NTAB - 2);
                float f = u - (float)i;
                float2 tv = gtab[i];
                float xg = fmaf(f, tv.y, tv.x) * x;
                if (mt < 2)       s0 += xg;    // rows wm+0..31  -> group lgb
                else if (mt == 2) t2 += xg;    // rows wm+32..47 -> straddle on q4
                else              s1 += xg;    // rows wm+48..79 -> group lgb+1
            }
        }
        bool lo = (q4 < 2);
        s0 += lo ? t2 : 0.f;
        s1 += lo ? 0.f : t2;
        s0 += __shfl_xor(s0, 16); s0 += __shfl_xor(s0, 32);
        s1 += __shfl_xor(s1, 16); s1 += __shfl_xor(s1, 32);
        if (q4 == 0) {
            int col = wn + nt * 16 + r15;
            ph2[lgb][col]     = s0 * inv40;
            ph2[lgb + 1][col] = s1 * inv40;
        }
    }
    __syncthreads();

    // ---- phase 2: gate2 (tanhf, range-safe) + i-sum -> 12 final outputs ----
    float w2[CH], b2[CH], v2[CH];
    #pragma unroll
    for (int c = 0; c < CH; ++c) { w2[c] = fc1_w[c]; b2[c] = fc1_b[c]; v2[c] = fc2_w[c]; }

    #pragma unroll
    for (int r = 0; r < 3; ++r) {              // k-group r, l-group wv
        float x = (lane < PB) ? ph2[wv][r * PB + lane] : 0.f;
        float s = gate_ref(x, w2, b2, v2) * x;
        #pragma unroll
        for (int off = 32; off; off >>= 1) s += __shfl_xor(s, off);
        if (lane == 0)
            out[(size_t)(blockIdx.x * 3 + r) * KTR + blockIdx.y * 4 + wv] = s * inv40;
    }
}

extern "C" void kernel_launch(void* const* d_in, const int* in_sizes, int n_in,
                              void* d_out, int out_size, void* d_ws, size_t ws_size,
                              hipStream_t stream) {
    const float* enroll = (const float*)d_in[0];
    const float* test   = (const float*)d_in[1];
    const float* fc1_w  = (const float*)d_in[2];
    const float* fc1_b  = (const float*)d_in[3];
    const float* fc2_w  = (const float*)d_in[4];
    float* out = (float*)d_out;

    _Float16* XT = (_Float16*)d_ws;                    // [3840][512] f16 (test:  hi|lo')
    _Float16* XE = XT + (size_t)MDIM * KK;             // [3840][512] f16 (enroll: lo'|hi)
    float2* gtabG = (float2*)(XE + (size_t)MDIM * KK);

    k_norm<<<2 * KTR + 9, 256, 0, stream>>>(enroll, test, fc1_w, fc1_b, fc2_w, XT, XE, gtabG);
    dim3 g2(MDIM / BNV, MDIM / BM);                    // (32, 24) = 768 blocks
    k_gemm<<<g2, 256, 0, stream>>>(XT, XE, gtabG, fc1_w, fc1_b, fc2_w, out);
}

// Round 7
// 112.277 us; speedup vs baseline: 1.7486x; 1.7486x over previous
//
#include <hip/hip_runtime.h>
#include <math.h>

#define KTR 96
#define DIM 256
#define PB  40
#define CH  8
#define MDIM 3840
#define KK  512             // A(test): [hi | lo*4096]; B(enroll): [lo*4096 | hi]
#define BM 160              // test rows (l,j): 4 complete groups
#define BNS 128             // enroll cols staged
#define BNV 120             // enroll cols valid: 3 complete groups
#define BK 32
#define LDR 40              // f16 per LDS row: 32 data + 8 pad (80 B stride) — round-3 proven
#define NTAB 2113           // gate table nodes, h = 2^-10, x = (i-1056)/1024

typedef _Float16 v8h __attribute__((ext_vector_type(8)));
typedef float    v4f __attribute__((ext_vector_type(4)));

__device__ __forceinline__ float gate_ref(float x, const float* w, const float* b, const float* v) {
    float g = 0.f;
    #pragma unroll
    for (int c = 0; c < CH; ++c) g = fmaf(v[c], tanhf(fmaf(w[c], x, b[c])), g);
    return g;
}

// ---------------- Kernel 1: L2-normalize + f16 hi/lo split (compact rows) + gate table ----------------
__global__ __launch_bounds__(256) void k_norm(const float* __restrict__ enroll,
                                              const float* __restrict__ test,
                                              const float* __restrict__ fc1_w,
                                              const float* __restrict__ fc1_b,
                                              const float* __restrict__ fc2_w,
                                              _Float16* __restrict__ XT,
                                              _Float16* __restrict__ XE,
                                              float2* __restrict__ gtabG) {
    int b = blockIdx.x, tid = threadIdx.x;

    if (b >= 2 * KTR) {                        // 9 table-builder blocks
        int i = (b - 2 * KTR) * 256 + tid;
        if (i < NTAB) {
            float w[CH], bb[CH], vv[CH];
            #pragma unroll
            for (int c = 0; c < CH; ++c) { w[c] = fc1_w[c]; bb[c] = fc1_b[c]; vv[c] = fc2_w[c]; }
            float x0 = (float)(i - 1056) * 0.0009765625f;
            float g0 = gate_ref(x0, w, bb, vv);
            float g1 = gate_ref(x0 + 0.0009765625f, w, bb, vv);
            gtabG[i] = make_float2(g0, g1 - g0);
        }
        return;
    }

    bool isE = (b < KTR);
    int k = isE ? b : b - KTR;
    const float* src = (isE ? enroll : test) + (size_t)k * DIM * PB;

    __shared__ float S[DIM * 41];
    __shared__ float part[6 * PB];
    __shared__ float rn[PB];

    for (int i = tid; i < DIM * PB / 4; i += 256) {
        float4 v = ((const float4*)src)[i];
        int d = i / 10, c = i - d * 10;
        float* p = &S[d * 41 + c * 4];
        p[0] = v.x; p[1] = v.y; p[2] = v.z; p[3] = v.w;
    }
    __syncthreads();
    if (tid < 240) {
        int g = tid / PB, p = tid - (tid / PB) * PB;
        float acc = 0.f;
        for (int d = g; d < DIM; d += 6) {
            float x = S[d * 41 + p];
            acc = fmaf(x, x, acc);
        }
        part[g * PB + p] = acc;
    }
    __syncthreads();
    if (tid < PB) {
        float s = 0.f;
        #pragma unroll
        for (int g = 0; g < 6; ++g) s += part[g * PB + tid];
        rn[tid] = 1.0f / fmaxf(sqrtf(s), 1e-12f);
    }
    __syncthreads();

    // 1280 jobs: (p, 8-wide d-group) -> two uint4 stores (hi, lo')
    _Float16* dst = isE ? XE : XT;
    #pragma unroll
    for (int i = 0; i < 5; ++i) {
        int idx = tid + i * 256;
        int p = idx >> 5, dg = idx & 31;
        int d0 = dg * 8;
        float r = rn[p];
        union { _Float16 f[8]; uint4 u; } hv, lv;
        #pragma unroll
        for (int j = 0; j < 8; ++j) {
            float x = S[(d0 + j) * 41 + p] * r;
            _Float16 h = (_Float16)x;
            hv.f[j] = h;
            lv.f[j] = (_Float16)((x - (float)h) * 4096.0f);
        }
        size_t base = (size_t)(k * PB + p) * KK;
        if (isE) {  // enroll: [lo' | hi]
            *(uint4*)(dst + base + d0)       = lv.u;
            *(uint4*)(dst + base + 256 + d0) = hv.u;
        } else {    // test:   [hi | lo']
            *(uint4*)(dst + base + d0)       = hv.u;
            *(uint4*)(dst + base + 256 + d0) = lv.u;
        }
    }
}

// ---------------- Kernel 2: round-3 BK=32 reg-staged K-loop + fused two-gate epilogue ----------------
// launch_bounds(256,3): this exact staging shape (4.5 uint4/thread) compiled at VGPR~100
// with zero spill in rounds 2-3. Do NOT grow staging regs (round 5/6: 9 uint4 -> 200+ MB
// scratch spill traffic regardless of bounds).
__global__ __launch_bounds__(256, 3) void k_gemm(const _Float16* __restrict__ XT,
                                                 const _Float16* __restrict__ XE,
                                                 const float2* __restrict__ gtab,
                                                 const float* __restrict__ fc1_w,
                                                 const float* __restrict__ fc1_b,
                                                 const float* __restrict__ fc2_w,
                                                 float* __restrict__ out) {
    __shared__ __align__(16) _Float16 LA[BM * LDR];    // 12800 B
    __shared__ __align__(16) _Float16 LB[BNS * LDR];   // 10240 B
    __shared__ float ph2[4][132];                      // block-local pho2 [lgroup][col]

    int tid = threadIdx.x, lane = tid & 63, wv = tid >> 6;
    int m0 = blockIdx.y * BM;
    int n0 = blockIdx.x * BNV;                         // steps of 120; stages 128 (8 masked)

    int arow = tid >> 2, aqc = tid & 3;                // 64 rows x 4 16B-chunks per step
    const uint4* gT  = (const uint4*)(XT + (size_t)(m0 + arow) * KK);        // 64 uint4/row
    int r0 = n0 + arow;      if (r0 > MDIM - 1) r0 = MDIM - 1;
    int r1 = n0 + arow + 64; if (r1 > MDIM - 1) r1 = MDIM - 1;
    const uint4* gB0 = (const uint4*)(XE + (size_t)r0 * KK);
    const uint4* gB1 = (const uint4*)(XE + (size_t)r1 * KK);
    uint4* lA = (uint4*)LA + (arow * 5 + aqc);         // LDR f16 = 5 uint4 per row
    uint4* lB = (uint4*)LB + (arow * 5 + aqc);

    int wm = (wv & 1) * 80;
    int wn = (wv >> 1) * 64;
    int r15 = lane & 15, q4 = lane >> 4;

    int aoff[5], boff[4];
    #pragma unroll
    for (int mt = 0; mt < 5; ++mt) aoff[mt] = (wm + mt * 16 + r15) * LDR + q4 * 8;
    #pragma unroll
    for (int nt = 0; nt < 4; ++nt) boff[nt] = (wn + nt * 16 + r15) * LDR + q4 * 8;

    v4f acc[5][4];
    #pragma unroll
    for (int mt = 0; mt < 5; ++mt)
        #pragma unroll
        for (int nt = 0; nt < 4; ++nt)
            acc[mt][nt] = (v4f)0.f;

    uint4 va0, va1, va2, vb0, vb1;
    // iters 0..15: A [hi|lo'] vs B [lo'|hi] (cross terms x4096); 16..23: hi vs hi
    #define GLOAD(IT) {                                                      \
        int ka = ((IT) < 16) ? (IT) * BK : ((IT) - 16) * BK;                 \
        int kb = ((IT) < 16) ? (IT) * BK : 256 + ((IT) - 16) * BK;           \
        int ia = (ka >> 3) + aqc, ib = (kb >> 3) + aqc;                      \
        va0 = gT[ia]; va1 = gT[ia + 64 * 64];                                \
        if (tid < 128) va2 = gT[ia + 128 * 64];                              \
        vb0 = gB0[ib]; vb1 = gB1[ib]; }

    GLOAD(0);
    for (int it = 0; it < 24; ++it) {
        __syncthreads();                       // prev iter's frag reads done
        lA[0]   = va0;
        lA[320] = va1;                         // +64 rows * 5 chunks
        if (tid < 128) lA[640] = va2;          // rows 128..159
        lB[0]   = vb0;
        lB[320] = vb1;
        __syncthreads();
        if (it < 23) GLOAD(it + 1);            // flies across the whole MFMA phase

        if (it == 16) {                        // cross complete: scale by 2^-12 (exact)
            #pragma unroll
            for (int mt = 0; mt < 5; ++mt)
                #pragma unroll
                for (int nt = 0; nt < 4; ++nt)
                    acc[mt][nt] *= 0.000244140625f;
        }

        v8h af[5], bf[4];
        #pragma unroll
        for (int mt = 0; mt < 5; ++mt) af[mt] = *(const v8h*)(LA + aoff[mt]);
        #pragma unroll
        for (int nt = 0; nt < 4; ++nt) bf[nt] = *(const v8h*)(LB + boff[nt]);
        #pragma unroll
        for (int mt = 0; mt < 5; ++mt)
            #pragma unroll
            for (int nt = 0; nt < 4; ++nt)
                acc[mt][nt] = __builtin_amdgcn_mfma_f32_16x16x32_f16(af[mt], bf[nt], acc[mt][nt], 0, 0, 0);
    }
    #undef GLOAD

    // ---- phase 1: gate1 (global table) + j-sum within wave -> ph2[lgroup][col] ----
    const float inv40 = 1.0f / (40.0f + 1e-6f);
    int lgb = wm / 40;                         // 0 or 2 (block-local l-group base)
    #pragma unroll
    for (int nt = 0; nt < 4; ++nt) {
        float s0 = 0.f, s1 = 0.f, t2 = 0.f;
        #pragma unroll
        for (int mt = 0; mt < 5; ++mt) {
            #pragma unroll
            for (int r = 0; r < 4; ++r) {
                float x = acc[mt][nt][r];
                float u = fmaf(x, 1024.0f, 1056.0f);
                int i = (int)u;
                i = min(max(i, 0), NTAB - 2);
                float f = u - (float)i;
                float2 tv = gtab[i];
                float xg = fmaf(f, tv.y, tv.x) * x;
                if (mt < 2)       s0 += xg;    // rows wm+0..31  -> group lgb
                else if (mt == 2) t2 += xg;    // rows wm+32..47 -> straddle on q4
                else              s1 += xg;    // rows wm+48..79 -> group lgb+1
            }
        }
        bool lo = (q4 < 2);
        s0 += lo ? t2 : 0.f;
        s1 += lo ? 0.f : t2;
        s0 += __shfl_xor(s0, 16); s0 += __shfl_xor(s0, 32);
        s1 += __shfl_xor(s1, 16); s1 += __shfl_xor(s1, 32);
        if (q4 == 0) {
            int col = wn + nt * 16 + r15;
            ph2[lgb][col]     = s0 * inv40;
            ph2[lgb + 1][col] = s1 * inv40;
        }
    }
    __syncthreads();

    // ---- phase 2: gate2 (tanhf, range-safe) + i-sum -> 12 final outputs ----
    float w2[CH], b2[CH], v2[CH];
    #pragma unroll
    for (int c = 0; c < CH; ++c) { w2[c] = fc1_w[c]; b2[c] = fc1_b[c]; v2[c] = fc2_w[c]; }

    #pragma unroll
    for (int r = 0; r < 3; ++r) {              // enroll k-group r, test l-group wv
        float x = (lane < PB) ? ph2[wv][r * PB + lane] : 0.f;
        float s = gate_ref(x, w2, b2, v2) * x;
        #pragma unroll
        for (int off = 32; off; off >>= 1) s += __shfl_xor(s, off);
        if (lane == 0)
            out[(size_t)(blockIdx.x * 3 + r) * KTR + blockIdx.y * 4 + wv] = s * inv40;
    }
}

extern "C" void kernel_launch(void* const* d_in, const int* in_sizes, int n_in,
                              void* d_out, int out_size, void* d_ws, size_t ws_size,
                              hipStream_t stream) {
    const float* enroll = (const float*)d_in[0];
    const float* test   = (const float*)d_in[1];
    const float* fc1_w  = (const float*)d_in[2];
    const float* fc1_b  = (const float*)d_in[3];
    const float* fc2_w  = (const float*)d_in[4];
    float* out = (float*)d_out;

    _Float16* XT = (_Float16*)d_ws;                    // [3840][512] f16 (test:  hi|lo')
    _Float16* XE = XT + (size_t)MDIM * KK;             // [3840][512] f16 (enroll: lo'|hi)
    float2* gtabG = (float2*)(XE + (size_t)MDIM * KK);

    k_norm<<<2 * KTR + 9, 256, 0, stream>>>(enroll, test, fc1_w, fc1_b, fc2_w, XT, XE, gtabG);
    dim3 g2(MDIM / BNV, MDIM / BM);                    // (32, 24) = 768 blocks = 3/CU
    k_gemm<<<g2, 256, 0, stream>>>(XT, XE, gtabG, fc1_w, fc1_b, fc2_w, out);
}